// Round 1
// baseline (70.520 us; speedup 1.0000x reference)
//
#include <hip/hip_runtime.h>

#define Nn 768
#define Dd 128
#define LDP 136   // padded LDS row length in bf16 elems (272 B, 16B-aligned, ~2-way banks)

typedef __attribute__((ext_vector_type(8))) short bf16x8;
typedef __attribute__((ext_vector_type(4))) float f32x4;
typedef __attribute__((ext_vector_type(4))) int   i32x4;

static __device__ __forceinline__ unsigned short f2bf(float f) {
  unsigned int u = __builtin_bit_cast(unsigned int, f);
  u += 0x7fffu + ((u >> 16) & 1u);   // RNE
  return (unsigned short)(u >> 16);
}
static __device__ __forceinline__ float bf2f(unsigned short h) {
  unsigned int u = ((unsigned int)h) << 16;
  return __builtin_bit_cast(float, u);
}

// left[i][e] = sum_d x[i][d] * W_in[e][d] + b_in[e], stored bf16
__global__ __launch_bounds__(128)
void k_left(const float* __restrict__ x, const float* __restrict__ Win,
            const float* __restrict__ bin, unsigned short* __restrict__ left) {
  __shared__ float sx[Dd];
  const int i = blockIdx.x;
  const int e = threadIdx.x;
  sx[e] = x[i * Dd + e];
  __syncthreads();
  const float4* wrow = (const float4*)(Win + e * Dd);
  float acc = bin[e];
#pragma unroll
  for (int d4 = 0; d4 < Dd / 4; ++d4) {
    float4 w = wrow[d4];
    acc += sx[4*d4+0]*w.x + sx[4*d4+1]*w.y + sx[4*d4+2]*w.z + sx[4*d4+3]*w.w;
  }
  left[i * Dd + e] = f2bf(acc);
}

// out[i, j, e] = sum_d left[j][d] * (left[i][d] * W_out[e][d]) + b_out[e]
// One block: one i, one 128-row j-tile. C tile = 128(j) x 128(e), K = 128.
__global__ __launch_bounds__(256, 2)
void k_outer(const unsigned short* __restrict__ left, const float* __restrict__ Wout,
             const float* __restrict__ bout, float* __restrict__ out) {
  __shared__ __attribute__((aligned(16))) unsigned short sA[128 * LDP]; // left[j-tile][d]
  __shared__ __attribute__((aligned(16))) unsigned short sB[128 * LDP]; // B[e][d] = Wout[e][d]*left_i[d]
  __shared__ float sLi[Dd];
  __shared__ float sBo[Dd];

  const int jt = blockIdx.x;   // 0..5
  const int i  = blockIdx.y;   // 0..767
  const int t  = threadIdx.x;  // 0..255

  if (t < Dd) {
    sLi[t] = bf2f(left[i * Dd + t]);
    sBo[t] = bout[t];
  }
  __syncthreads();

  // Stage sA (left j-tile, bf16 passthrough) and sB (scaled W_out rows -> bf16).
  {
    const int row = t >> 4;          // 0..15
    const int c8  = (t & 15) * 8;    // column chunk of 8 elems
#pragma unroll
    for (int it = 0; it < 8; ++it) {
      const int r = row + it * 16;   // 0..127
      // A: 16B bf16 copy, fully coalesced
      i32x4 va = *(const i32x4*)(left + (jt * 128 + r) * Dd + c8);
      *(i32x4*)(sA + r * LDP + c8) = va;
      // B: read 8 f32 of W_out row r, scale by left_i[d], convert to bf16
      const float4* wp = (const float4*)(Wout + r * Dd + c8);
      float4 w0 = wp[0], w1 = wp[1];
      unsigned int p0 = (unsigned int)f2bf(w0.x * sLi[c8+0]) | ((unsigned int)f2bf(w0.y * sLi[c8+1]) << 16);
      unsigned int p1 = (unsigned int)f2bf(w0.z * sLi[c8+2]) | ((unsigned int)f2bf(w0.w * sLi[c8+3]) << 16);
      unsigned int p2 = (unsigned int)f2bf(w1.x * sLi[c8+4]) | ((unsigned int)f2bf(w1.y * sLi[c8+5]) << 16);
      unsigned int p3 = (unsigned int)f2bf(w1.z * sLi[c8+6]) | ((unsigned int)f2bf(w1.w * sLi[c8+7]) << 16);
      i32x4 vb; vb[0] = (int)p0; vb[1] = (int)p1; vb[2] = (int)p2; vb[3] = (int)p3;
      *(i32x4*)(sB + r * LDP + c8) = vb;
    }
  }
  __syncthreads();

  const int wid  = t >> 6;        // wave 0..3 -> j rows [wid*32, wid*32+32)
  const int lane = t & 63;
  const int l15  = lane & 15;
  const int kq   = (lane >> 4) * 8;  // k-offset within 32-wide k-block

  f32x4 acc[2][8] = {};

#pragma unroll
  for (int kb = 0; kb < 4; ++kb) {
    const int k = kb * 32 + kq;
    bf16x8 a0 = *(const bf16x8*)(sA + (wid * 32 +      l15) * LDP + k);
    bf16x8 a1 = *(const bf16x8*)(sA + (wid * 32 + 16 + l15) * LDP + k);
#pragma unroll
    for (int eb = 0; eb < 8; ++eb) {
      bf16x8 b = *(const bf16x8*)(sB + (eb * 16 + l15) * LDP + k);
      acc[0][eb] = __builtin_amdgcn_mfma_f32_16x16x32_bf16(a0, b, acc[0][eb], 0, 0, 0);
      acc[1][eb] = __builtin_amdgcn_mfma_f32_16x16x32_bf16(a1, b, acc[1][eb], 0, 0, 0);
    }
  }

  // Epilogue: C row = (lane>>4)*4 + r (j), col = lane&15 (e). Add bias, store f32.
#pragma unroll
  for (int jb = 0; jb < 2; ++jb) {
#pragma unroll
    for (int r = 0; r < 4; ++r) {
      const int j = jt * 128 + wid * 32 + jb * 16 + (lane >> 4) * 4 + r;
      float* orow = out + ((size_t)i * Nn + j) * Dd;
#pragma unroll
      for (int eb = 0; eb < 8; ++eb) {
        const int e = eb * 16 + l15;
        orow[e] = acc[jb][eb][r] + sBo[e];
      }
    }
  }
}

extern "C" void kernel_launch(void* const* d_in, const int* in_sizes, int n_in,
                              void* d_out, int out_size, void* d_ws, size_t ws_size,
                              hipStream_t stream) {
  const float* x    = (const float*)d_in[0];
  const float* Win  = (const float*)d_in[1];
  const float* bin  = (const float*)d_in[2];
  const float* Wout = (const float*)d_in[3];
  const float* bout = (const float*)d_in[4];
  float* out = (float*)d_out;
  unsigned short* left = (unsigned short*)d_ws;  // 768*128 bf16 = 192 KiB

  k_left<<<Nn, Dd, 0, stream>>>(x, Win, bin, left);
  dim3 grid(Nn / 128, Nn);
  k_outer<<<grid, 256, 0, stream>>>(left, Wout, bout, out);
}